// Round 1
// baseline (9067.248 us; speedup 1.0000x reference)
//
#include <hip/hip_runtime.h>
#include <hip/hip_bf16.h>

// LSTM: T=512, B=64, D_IN=512, D_LAT=1024.
// Phase 1: xg[t,b,g] = x @ Wx^T + b  (bf16 MFMA, output stored bf16, pre-permuted
//          into phase-2 fragment order).
// Phase 2: persistent kernel, 128 WGs x 256 thr. Each WG owns 8 latent columns
//          (=32 gate columns f/i/c/o). Wh fragments live in VGPRs (256/lane).
//          Per step: read h_{t-1} (bf16, double-buffered in ws) directly from
//          global as MFMA A-fragments, 64 MFMAs/wave, gate math in-register,
//          c-state in VGPRs, grid barrier via device-scope atomic counter.

typedef __attribute__((ext_vector_type(8))) short short8;
typedef __attribute__((ext_vector_type(4))) short short4v;
typedef __attribute__((ext_vector_type(4))) float f32x4;

#define T_STEPS 512
#define BATCH   64
#define DIN     512
#define DLAT    1024
#define NWG     128     // phase-2 workgroups (latent 1024 / 8 per WG)
#define LPW     8       // latent columns per WG

#define WS_BAR  0
#define WS_H    4096                     // 2 * 64*1024 ushort = 262144 B
#define WS_XG   (4096 + 262144)          // 512*128*4*2*64*4 ushort = 256 MiB

#define MFMA(a, b, c) __builtin_amdgcn_mfma_f32_16x16x32_bf16((a), (b), (c), 0, 0, 0)

static __device__ __forceinline__ unsigned short f2bf(float f) {
  unsigned u = __builtin_bit_cast(unsigned, f);
  u = (u + 0x7FFFu + ((u >> 16) & 1u)) >> 16;   // RNE
  return (unsigned short)u;
}
static __device__ __forceinline__ float bf2f(unsigned short s) {
  unsigned u = ((unsigned)s) << 16;
  return __builtin_bit_cast(float, u);
}
static __device__ __forceinline__ float sigf(float x) {
  return 1.0f / (1.0f + __expf(-x));            // NaN-safe both tails
}
static __device__ __forceinline__ float tanhfast(float x) {
  return 2.0f / (1.0f + __expf(-2.0f * x)) - 1.0f;
}
static __device__ __forceinline__ short8 packbf(f32x4 a, f32x4 b) {
  short8 s;
  s[0]=(short)f2bf(a[0]); s[1]=(short)f2bf(a[1]); s[2]=(short)f2bf(a[2]); s[3]=(short)f2bf(a[3]);
  s[4]=(short)f2bf(b[0]); s[5]=(short)f2bf(b[1]); s[6]=(short)f2bf(b[2]); s[7]=(short)f2bf(b[3]);
  return s;
}

// ---------------- Phase 1: xg = x @ Wx^T + bias -----------------------------
// grid (32, 512): blockIdx.x = N-block (4 phase-2 wgs), blockIdx.y = t-block.
// Each of 4 waves handles one phase-2 wg's 32 gate columns; B (Wx slice) in
// registers, x tile staged bf16 in LDS with XOR swizzle.
__global__ __launch_bounds__(256, 2) void lstm_phase1(
    const float* __restrict__ x,
    const float* __restrict__ Wf, const float* __restrict__ bfp,
    const float* __restrict__ Wi, const float* __restrict__ bip,
    const float* __restrict__ Wc, const float* __restrict__ bcp,
    const float* __restrict__ Wo, const float* __restrict__ bop,
    unsigned short* __restrict__ xg)
{
  __shared__ __align__(16) short lds[BATCH * DIN];   // bf16 bits, swizzled
  const int tid  = threadIdx.x;
  const int nb   = blockIdx.x;    // 0..31
  const int tb   = blockIdx.y;    // 0..511
  const int lane = tid & 63;
  const int wv   = tid >> 6;      // wave 0..3
  const int cc   = lane & 15;
  const int q    = lane >> 4;

  // stage x tile (64 x 512) -> bf16 LDS, swizzled: byte ^= (row&7)<<4
  const float* xs = x + (size_t)tb * (BATCH * DIN);
  #pragma unroll
  for (int it = 0; it < 16; ++it) {
    int c = tid + 256 * it;
    int row = c >> 6, kc = c & 63;
    const f32x4* p = (const f32x4*)(xs + row * DIN + kc * 8);
    f32x4 v0 = p[0], v1 = p[1];
    int byte = (row * (DIN * 2) + kc * 16) ^ ((row & 7) << 4);
    *(short8*)((char*)lds + byte) = packbf(v0, v1);
  }

  // B preload: this wave serves phase-2 wg = nb*4 + wv
  const int wg = nb * 4 + wv;
  const int jj = wg * LPW + (cc & 7);
  short8 bw[2][16];
  #pragma unroll
  for (int T = 0; T < 2; ++T) {
    const float* Wp = (T == 0) ? (cc < 8 ? Wf : Wi) : (cc < 8 ? Wc : Wo);
    const float* base = Wp + (size_t)jj * (DIN + DLAT);   // Wx part: cols [0,512)
    #pragma unroll
    for (int k = 0; k < 16; ++k) {
      const f32x4* p = (const f32x4*)(base + k * 32 + q * 8);
      bw[T][k] = packbf(p[0], p[1]);
    }
  }
  __syncthreads();

  f32x4 acc[4][2] = {};
  #pragma unroll
  for (int k = 0; k < 16; ++k) {
    #pragma unroll
    for (int m = 0; m < 4; ++m) {
      int row = m * 16 + cc;
      int byte = (row * (DIN * 2) + (k * 32 + q * 8) * 2) ^ ((row & 7) << 4);
      short8 a = *(const short8*)((const char*)lds + byte);
      acc[m][0] = MFMA(a, bw[0][k], acc[m][0]);
      acc[m][1] = MFMA(a, bw[1][k], acc[m][1]);
    }
  }

  // bias + store bf16 in phase-2 fragment order:
  // idx = (((tb*128 + wg)*4 + m)*2 + T)*64 + lane, 4 values each
  #pragma unroll
  for (int T = 0; T < 2; ++T) {
    const float* Bp = (T == 0) ? (cc < 8 ? bfp : bip) : (cc < 8 ? bcp : bop);
    float bias = Bp[jj];
    #pragma unroll
    for (int m = 0; m < 4; ++m) {
      f32x4 g = acc[m][T];
      short4v s;
      s[0] = (short)f2bf(g[0] + bias);
      s[1] = (short)f2bf(g[1] + bias);
      s[2] = (short)f2bf(g[2] + bias);
      s[3] = (short)f2bf(g[3] + bias);
      size_t idx = ((((size_t)tb * NWG + wg) * 4 + m) * 2 + T) * 64 + lane;
      *(short4v*)(xg + idx * 4) = s;
    }
  }
}

// ---------------- Phase 2: persistent recurrence ----------------------------
__global__ __launch_bounds__(256, 1) void lstm_phase2(
    const float* __restrict__ Wf, const float* __restrict__ Wi,
    const float* __restrict__ Wc, const float* __restrict__ Wo,
    const unsigned short* __restrict__ xg,
    unsigned short* __restrict__ hbuf,      // 2 x 64 x 1024 bf16 bits
    unsigned int* __restrict__ bar,
    float* __restrict__ out)
{
  const int tid  = threadIdx.x;
  const int lane = tid & 63;
  const int wv   = tid >> 6;        // M-tile (batch group) 0..3
  const int wg   = blockIdx.x;      // 0..127
  const int cc   = lane & 15;
  const int q    = lane >> 4;
  const int jj   = wg * LPW + (cc & 7);

  // Wh fragments -> registers (2 tiles x 32 k-steps x 4 VGPR = 256 VGPR/lane)
  short8 wh[2][32];
  #pragma unroll
  for (int T = 0; T < 2; ++T) {
    const float* Wp = (T == 0) ? (cc < 8 ? Wf : Wi) : (cc < 8 ? Wc : Wo);
    const float* base = Wp + (size_t)jj * (DIN + DLAT) + DIN;  // Wh part
    #pragma unroll
    for (int k = 0; k < 32; ++k) {
      const f32x4* p = (const f32x4*)(base + k * 32 + q * 8);
      wh[T][k] = packbf(p[0], p[1]);
    }
  }

  f32x4 cst = {0.f, 0.f, 0.f, 0.f};        // cell state, lives in VGPRs
  const unsigned short* xgp = xg + (((size_t)wg * 4 + wv) * 2) * 256 + (size_t)lane * 4;
  const size_t xg_stride = (size_t)NWG * 4 * 2 * 256;   // per-t: 262144 ushorts
  const int arow = wv * 16 + cc;            // batch row for A fragments
  unsigned tgt = NWG;

  for (int t = 0; t < T_STEPS; ++t) {
    f32x4 acc0 = {0.f,0.f,0.f,0.f}, acc1 = {0.f,0.f,0.f,0.f};
    if (t > 0) {
      const unsigned short* h = hbuf + (((t & 1) ^ 1) << 16) + arow * DLAT + q * 8;
      short8 a[16];
      #pragma unroll
      for (int k = 0; k < 16; ++k) a[k] = *(const short8*)(h + k * 32);
      #pragma unroll
      for (int k = 0; k < 16; ++k) {
        acc0 = MFMA(a[k], wh[0][k], acc0);
        acc1 = MFMA(a[k], wh[1][k], acc1);
      }
      #pragma unroll
      for (int k = 0; k < 16; ++k) a[k] = *(const short8*)(h + 512 + k * 32);
      #pragma unroll
      for (int k = 0; k < 16; ++k) {
        acc0 = MFMA(a[k], wh[0][16 + k], acc0);
        acc1 = MFMA(a[k], wh[1][16 + k], acc1);
      }
    }

    // add xg (pre-permuted bf16)
    short4v x0 = *(const short4v*)(xgp);
    short4v x1 = *(const short4v*)(xgp + 256);
    xgp += xg_stride;
    f32x4 g0, g1;
    #pragma unroll
    for (int r = 0; r < 4; ++r) {
      g0[r] = acc0[r] + bf2f((unsigned short)x0[r]);
      g1[r] = acc1[r] + bf2f((unsigned short)x1[r]);
    }

    // exchange halves: tile0 = [F|I], tile1 = [C|O] along cols; partner = lane^8
    f32x4 g0x, g1x;
    #pragma unroll
    for (int r = 0; r < 4; ++r) {
      g0x[r] = __shfl_xor(g0[r], 8, 64);
      g1x[r] = __shfl_xor(g1[r], 8, 64);
    }
    const bool lo = (cc < 8);
    float hv[4];
    #pragma unroll
    for (int r = 0; r < 4; ++r) {
      float fpre = lo ? g0[r]  : g0x[r];
      float ipre = lo ? g0x[r] : g0[r];
      float cpre = lo ? g1[r]  : g1x[r];
      float opre = lo ? g1x[r] : g1[r];
      float fg = sigf(fpre), ig = sigf(ipre), cd = tanhfast(cpre), og = sigf(opre);
      float cn = fg * cst[r] + ig * cd;
      cst[r] = cn;
      hv[r] = og * tanhfast(cn);
    }

    if (lo) {   // lanes cc<8 own the results (cc>=8 are duplicates)
      unsigned short* hw = hbuf + ((t & 1) << 16);
      float* op = out + (size_t)t * (BATCH * DLAT);
      #pragma unroll
      for (int r = 0; r < 4; ++r) {
        int b = wv * 16 + q * 4 + r;
        hw[b * DLAT + jj] = f2bf(hv[r]);
        op[b * DLAT + jj] = hv[r];
      }
    }

    // grid barrier: device-scope atomic counter, monotonic
    __syncthreads();
    if (tid == 0) {
      __hip_atomic_fetch_add(bar, 1u, __ATOMIC_RELEASE, __HIP_MEMORY_SCOPE_AGENT);
      while (__hip_atomic_load(bar, __ATOMIC_RELAXED, __HIP_MEMORY_SCOPE_AGENT) < tgt) {
        __builtin_amdgcn_s_sleep(1);
      }
      __threadfence();   // acquire: invalidate L1/L2 so fresh h is visible
    }
    __syncthreads();
    tgt += NWG;
  }
}

extern "C" void kernel_launch(void* const* d_in, const int* in_sizes, int n_in,
                              void* d_out, int out_size, void* d_ws, size_t ws_size,
                              hipStream_t stream) {
  (void)in_sizes; (void)n_in; (void)out_size; (void)ws_size;
  const float* x   = (const float*)d_in[0];
  const float* Wf  = (const float*)d_in[1];
  const float* bfp = (const float*)d_in[2];
  const float* Wi  = (const float*)d_in[3];
  const float* bip = (const float*)d_in[4];
  const float* Wc  = (const float*)d_in[5];
  const float* bcp = (const float*)d_in[6];
  const float* Wo  = (const float*)d_in[7];
  const float* bop = (const float*)d_in[8];
  float* out = (float*)d_out;

  unsigned int*   bar  = (unsigned int*)d_ws;
  unsigned short* hbuf = (unsigned short*)((char*)d_ws + WS_H);
  unsigned short* xg   = (unsigned short*)((char*)d_ws + WS_XG);

  hipMemsetAsync(d_ws, 0, 256, stream);   // reset barrier counter each call
  lstm_phase1<<<dim3(32, 512), 256, 0, stream>>>(x, Wf, bfp, Wi, bip, Wc, bcp, Wo, bop, xg);
  lstm_phase2<<<dim3(NWG), 256, 0, stream>>>(Wf, Wi, Wc, Wo, xg, hbuf, bar, out);
}

// Round 2
// 6312.868 us; speedup vs baseline: 1.4363x; 1.4363x over previous
//
#include <hip/hip_runtime.h>
#include <hip/hip_bf16.h>

// LSTM: T=512, B=64, D_IN=512, D_LAT=1024.
// Phase 1: xg = x @ Wx^T + b (bf16 MFMA, pre-permuted bf16 output), 4 t-tiles/WG.
// Phase 2: persistent, 128 WGs x 256 thr, Wh in VGPRs. Sync rebuilt:
//   - per-WG flag array, relaxed agent-scope atomics only (no fences, no RMW,
//     no L2 writeback/invalidate instructions)
//   - h exchanged via relaxed agent-scope 8B atomic ld/st (IF$-coherent),
//     coalesced through a per-wave LDS transpose
//   - xg prefetched one step ahead during the poll window

typedef __attribute__((ext_vector_type(8))) short short8;
typedef __attribute__((ext_vector_type(4))) short short4v;
typedef __attribute__((ext_vector_type(4))) float f32x4;

#define T_STEPS 512
#define BATCH   64
#define DIN     512
#define DLAT    1024
#define NWG     128
#define LPW     8

#define WS_H    4096                     // 2 * 64*1024 ushort = 262144 B
#define WS_XG   (4096 + 262144)          // 512*128*4*2*64*4 ushort = 256 MiB

#define MFMA(a, b, c) __builtin_amdgcn_mfma_f32_16x16x32_bf16((a), (b), (c), 0, 0, 0)

static __device__ __forceinline__ unsigned short f2bf(float f) {
  unsigned u = __builtin_bit_cast(unsigned, f);
  u = (u + 0x7FFFu + ((u >> 16) & 1u)) >> 16;   // RNE
  return (unsigned short)u;
}
static __device__ __forceinline__ float bf2f(unsigned short s) {
  unsigned u = ((unsigned)s) << 16;
  return __builtin_bit_cast(float, u);
}
static __device__ __forceinline__ float sigf(float x) {
  return 1.0f / (1.0f + __expf(-x));
}
static __device__ __forceinline__ float tanhfast(float x) {
  return 2.0f / (1.0f + __expf(-2.0f * x)) - 1.0f;
}
static __device__ __forceinline__ short8 packbf(f32x4 a, f32x4 b) {
  short8 s;
  s[0]=(short)f2bf(a[0]); s[1]=(short)f2bf(a[1]); s[2]=(short)f2bf(a[2]); s[3]=(short)f2bf(a[3]);
  s[4]=(short)f2bf(b[0]); s[5]=(short)f2bf(b[1]); s[6]=(short)f2bf(b[2]); s[7]=(short)f2bf(b[3]);
  return s;
}

// ---------------- Phase 1: xg = x @ Wx^T + bias -----------------------------
__global__ __launch_bounds__(256, 2) void lstm_phase1(
    const float* __restrict__ x,
    const float* __restrict__ Wf, const float* __restrict__ bfp,
    const float* __restrict__ Wi, const float* __restrict__ bip,
    const float* __restrict__ Wc, const float* __restrict__ bcp,
    const float* __restrict__ Wo, const float* __restrict__ bop,
    unsigned short* __restrict__ xg)
{
  __shared__ __align__(16) short lds[BATCH * DIN];   // bf16 bits, swizzled
  const int tid  = threadIdx.x;
  const int nb   = blockIdx.x;    // 0..31
  const int tb4  = blockIdx.y;    // 0..127
  const int lane = tid & 63;
  const int wv   = tid >> 6;
  const int cc   = lane & 15;
  const int q    = lane >> 4;

  // B preload: this wave serves phase-2 wg = nb*4 + wv
  const int wg = nb * 4 + wv;
  const int jj = wg * LPW + (cc & 7);
  short8 bw[2][16];
  #pragma unroll
  for (int T = 0; T < 2; ++T) {
    const float* Wp = (T == 0) ? (cc < 8 ? Wf : Wi) : (cc < 8 ? Wc : Wo);
    const float* base = Wp + (size_t)jj * (DIN + DLAT);
    #pragma unroll
    for (int k = 0; k < 16; ++k) {
      const f32x4* p = (const f32x4*)(base + k * 32 + q * 8);
      bw[T][k] = packbf(p[0], p[1]);
    }
  }
  float biasv[2];
  biasv[0] = (cc < 8 ? bfp : bip)[jj];
  biasv[1] = (cc < 8 ? bcp : bop)[jj];

  for (int tt = 0; tt < 4; ++tt) {
    const int tb = tb4 * 4 + tt;

    // stage x tile (64 x 512) -> bf16 LDS, swizzled
    const float* xs = x + (size_t)tb * (BATCH * DIN);
    #pragma unroll
    for (int it = 0; it < 16; ++it) {
      int c = tid + 256 * it;
      int row = c >> 6, kc = c & 63;
      const f32x4* p = (const f32x4*)(xs + row * DIN + kc * 8);
      f32x4 v0 = p[0], v1 = p[1];
      int byte = (row * (DIN * 2) + kc * 16) ^ ((row & 7) << 4);
      *(short8*)((char*)lds + byte) = packbf(v0, v1);
    }
    __syncthreads();

    f32x4 acc[4][2] = {};
    #pragma unroll
    for (int k = 0; k < 16; ++k) {
      #pragma unroll
      for (int m = 0; m < 4; ++m) {
        int row = m * 16 + cc;
        int byte = (row * (DIN * 2) + (k * 32 + q * 8) * 2) ^ ((row & 7) << 4);
        short8 a = *(const short8*)((const char*)lds + byte);
        acc[m][0] = MFMA(a, bw[0][k], acc[m][0]);
        acc[m][1] = MFMA(a, bw[1][k], acc[m][1]);
      }
    }
    __syncthreads();   // LDS reuse next tt

    #pragma unroll
    for (int T = 0; T < 2; ++T) {
      float bias = biasv[T];
      #pragma unroll
      for (int m = 0; m < 4; ++m) {
        f32x4 g = acc[m][T];
        short4v s;
        s[0] = (short)f2bf(g[0] + bias);
        s[1] = (short)f2bf(g[1] + bias);
        s[2] = (short)f2bf(g[2] + bias);
        s[3] = (short)f2bf(g[3] + bias);
        size_t idx = ((((size_t)tb * NWG + wg) * 4 + m) * 2 + T) * 64 + lane;
        *(short4v*)(xg + idx * 4) = s;
      }
    }
  }
}

// ---------------- Phase 2: persistent recurrence ----------------------------
__global__ __launch_bounds__(256, 1) void lstm_phase2(
    const float* __restrict__ Wf, const float* __restrict__ Wi,
    const float* __restrict__ Wc, const float* __restrict__ Wo,
    const unsigned short* __restrict__ xg,
    unsigned short* __restrict__ hbuf,      // 2 x 64 x 1024 bf16 bits
    unsigned int* __restrict__ flags,       // NWG monotonic arrival flags
    float* __restrict__ out)
{
  const int tid  = threadIdx.x;
  const int lane = tid & 63;
  const int wv   = tid >> 6;        // M-tile (batch group) 0..3
  const int wg   = blockIdx.x;      // 0..127
  const int cc   = lane & 15;
  const int q    = lane >> 4;
  const int jj   = wg * LPW + (cc & 7);

  __shared__ unsigned short lds_h[4][16][8];
  __shared__ float          lds_o[4][16][8];

  // Wh fragments -> registers
  short8 wh[2][32];
  #pragma unroll
  for (int T = 0; T < 2; ++T) {
    const float* Wp = (T == 0) ? (cc < 8 ? Wf : Wi) : (cc < 8 ? Wc : Wo);
    const float* base = Wp + (size_t)jj * (DIN + DLAT) + DIN;
    #pragma unroll
    for (int k = 0; k < 32; ++k) {
      const f32x4* p = (const f32x4*)(base + k * 32 + q * 8);
      wh[T][k] = packbf(p[0], p[1]);
    }
  }

  f32x4 cst = {0.f, 0.f, 0.f, 0.f};
  const unsigned short* xbase = xg + (((size_t)wg * 4 + wv) * 2) * 256 + (size_t)lane * 4;
  const int arow = wv * 16 + cc;

  short4v xp0 = *(const short4v*)(xbase);
  short4v xp1 = *(const short4v*)(xbase + 256);

  for (int t = 0; t < T_STEPS; ++t) {
    // ---- wait for h_{t-1}: all flags >= t (relaxed agent loads, no fences)
    if (t > 0) {
      if (wv == 0) {
        const unsigned int* fp = flags + lane;
        for (;;) {
          unsigned a1 = __hip_atomic_load(fp,      __ATOMIC_RELAXED, __HIP_MEMORY_SCOPE_AGENT);
          unsigned a2 = __hip_atomic_load(fp + 64, __ATOMIC_RELAXED, __HIP_MEMORY_SCOPE_AGENT);
          if (__all(a1 >= (unsigned)t && a2 >= (unsigned)t)) break;
          __builtin_amdgcn_s_sleep(1);
        }
      }
      __syncthreads();
    }

    f32x4 acc0 = {0.f,0.f,0.f,0.f}, acc1 = {0.f,0.f,0.f,0.f};
    if (t > 0) {
      const unsigned long long* hq = (const unsigned long long*)
          (hbuf + (((t & 1) ^ 1) << 16) + arow * DLAT);
      // frag k (0..31): bytes q*16 + k*64  -> ull index q*2 + k*8
      short8 a[16];
      #pragma unroll
      for (int k = 0; k < 16; ++k) {
        unsigned long long lo = __hip_atomic_load(hq + q*2 + k*8,     __ATOMIC_RELAXED, __HIP_MEMORY_SCOPE_AGENT);
        unsigned long long hi = __hip_atomic_load(hq + q*2 + k*8 + 1, __ATOMIC_RELAXED, __HIP_MEMORY_SCOPE_AGENT);
        union { unsigned long long u[2]; short8 s; } cv; cv.u[0]=lo; cv.u[1]=hi;
        a[k] = cv.s;
      }
      #pragma unroll
      for (int k = 0; k < 16; ++k) {
        acc0 = MFMA(a[k], wh[0][k], acc0);
        acc1 = MFMA(a[k], wh[1][k], acc1);
      }
      #pragma unroll
      for (int k = 0; k < 16; ++k) {
        unsigned long long lo = __hip_atomic_load(hq + q*2 + (16+k)*8,     __ATOMIC_RELAXED, __HIP_MEMORY_SCOPE_AGENT);
        unsigned long long hi = __hip_atomic_load(hq + q*2 + (16+k)*8 + 1, __ATOMIC_RELAXED, __HIP_MEMORY_SCOPE_AGENT);
        union { unsigned long long u[2]; short8 s; } cv; cv.u[0]=lo; cv.u[1]=hi;
        a[k] = cv.s;
      }
      #pragma unroll
      for (int k = 0; k < 16; ++k) {
        acc0 = MFMA(a[k], wh[0][16 + k], acc0);
        acc1 = MFMA(a[k], wh[1][16 + k], acc1);
      }
    }

    // add xg (prefetched)
    f32x4 g0, g1;
    #pragma unroll
    for (int r = 0; r < 4; ++r) {
      g0[r] = acc0[r] + bf2f((unsigned short)xp0[r]);
      g1[r] = acc1[r] + bf2f((unsigned short)xp1[r]);
    }

    // exchange halves: tile0 = [F|I], tile1 = [C|O]; partner = lane^8
    f32x4 g0x, g1x;
    #pragma unroll
    for (int r = 0; r < 4; ++r) {
      g0x[r] = __shfl_xor(g0[r], 8, 64);
      g1x[r] = __shfl_xor(g1[r], 8, 64);
    }
    const bool lo = (cc < 8);
    float hv[4];
    #pragma unroll
    for (int r = 0; r < 4; ++r) {
      float fpre = lo ? g0[r]  : g0x[r];
      float ipre = lo ? g0x[r] : g0[r];
      float cpre = lo ? g1[r]  : g1x[r];
      float opre = lo ? g1x[r] : g1[r];
      float fg = sigf(fpre), ig = sigf(ipre), cd = tanhfast(cpre), og = sigf(opre);
      float cn = fg * cst[r] + ig * cd;
      cst[r] = cn;
      hv[r] = og * tanhfast(cn);
    }

    // transpose results through LDS for coalesced coherent stores
    if (lo) {
      #pragma unroll
      for (int r = 0; r < 4; ++r) {
        lds_h[wv][q * 4 + r][cc] = f2bf(hv[r]);
        lds_o[wv][q * 4 + r][cc] = hv[r];
      }
    }
    __syncthreads();

    {
      unsigned short* hw = hbuf + ((t & 1) << 16);
      float* op = out + (size_t)t * (BATCH * DLAT);
      if (lane < 32) {
        int row = lane >> 1, half = lane & 1;
        unsigned long long v = *(const unsigned long long*)&lds_h[wv][row][half * 4];
        int b = wv * 16 + row;
        __hip_atomic_store((unsigned long long*)(hw + b * DLAT + wg * LPW + half * 4), v,
                           __ATOMIC_RELAXED, __HIP_MEMORY_SCOPE_AGENT);
      }
      {
        int row = lane >> 2, quarter = lane & 3;
        unsigned long long v = *(const unsigned long long*)&lds_o[wv][row][quarter * 2];
        int b = wv * 16 + row;
        *(unsigned long long*)(op + b * DLAT + wg * LPW + quarter * 2) = v;
      }
    }

    // drain own stores to the coherence point, then arrive
    asm volatile("s_waitcnt vmcnt(0)" ::: "memory");
    __syncthreads();
    if (tid == 0)
      __hip_atomic_store(flags + wg, (unsigned)(t + 1), __ATOMIC_RELAXED, __HIP_MEMORY_SCOPE_AGENT);

    // prefetch next xg during the poll window
    {
      int tn = (t + 1 < T_STEPS) ? t + 1 : t;
      const unsigned short* xn = xbase + ((size_t)tn << 18);
      xp0 = *(const short4v*)(xn);
      xp1 = *(const short4v*)(xn + 256);
    }
  }
}

extern "C" void kernel_launch(void* const* d_in, const int* in_sizes, int n_in,
                              void* d_out, int out_size, void* d_ws, size_t ws_size,
                              hipStream_t stream) {
  (void)in_sizes; (void)n_in; (void)out_size; (void)ws_size;
  const float* x   = (const float*)d_in[0];
  const float* Wf  = (const float*)d_in[1];
  const float* bfp = (const float*)d_in[2];
  const float* Wi  = (const float*)d_in[3];
  const float* bip = (const float*)d_in[4];
  const float* Wc  = (const float*)d_in[5];
  const float* bcp = (const float*)d_in[6];
  const float* Wo  = (const float*)d_in[7];
  const float* bop = (const float*)d_in[8];
  float* out = (float*)d_out;

  unsigned int*   flags = (unsigned int*)d_ws;
  unsigned short* hbuf  = (unsigned short*)((char*)d_ws + WS_H);
  unsigned short* xg    = (unsigned short*)((char*)d_ws + WS_XG);

  hipMemsetAsync(d_ws, 0, 4096, stream);   // reset arrival flags each call
  lstm_phase1<<<dim3(32, 128), 256, 0, stream>>>(x, Wf, bfp, Wi, bip, Wc, bcp, Wo, bop, xg);
  lstm_phase2<<<dim3(NWG), 256, 0, stream>>>(Wf, Wi, Wc, Wo, xg, hbuf, flags, out);
}